// Round 16
// baseline (162.855 us; speedup 1.0000x reference)
//
#include <hip/hip_runtime.h>
#include <stdint.h>

#define BB 2
#define NN 4096
#define KNB 20
#define DD 128
#define PHH 8
#define AHH 512
#define BN (BB*NN)

typedef unsigned short ushort_t;
typedef short bf16x8 __attribute__((ext_vector_type(8)));
typedef float f32x4 __attribute__((ext_vector_type(4)));

__device__ __forceinline__ uint32_t umin32(uint32_t a, uint32_t b) { return a < b ? a : b; }
__device__ __forceinline__ uint32_t umax32(uint32_t a, uint32_t b) { return a > b ? a : b; }

__device__ __forceinline__ float bf2f(ushort_t u) {
    union { float f; uint32_t i; } c; c.i = ((uint32_t)u) << 16; return c.f;
}
__device__ __forceinline__ uint32_t cvt_pk_bf16(float lo, float hi) {
    uint32_t r;
    asm("v_cvt_pk_bf16_f32 %0, %1, %2" : "=v"(r) : "v"(lo), "v"(hi));
    return r;  // lo16 = bf16(lo), hi16 = bf16(hi)
}
__device__ __forceinline__ ushort_t f2bf(float f) {   // single-instr RNE via cvt_pk
    return (ushort_t)(cvt_pk_bf16(f, f) & 0xFFFFu);
}
__device__ __forceinline__ bf16x8 load_bfrag(const float* __restrict__ src) {
    float4 x = *(const float4*)src;
    float4 y = *(const float4*)(src + 4);
    union { bf16x8 v; uint32_t u[4]; } r;
    r.u[0] = cvt_pk_bf16(x.x, x.y);
    r.u[1] = cvt_pk_bf16(x.z, x.w);
    r.u[2] = cvt_pk_bf16(y.x, y.y);
    r.u[3] = cvt_pk_bf16(y.z, y.w);
    return r.v;
}

#define SW256(m, byteInRow) ((m)*256 + ((byteInRow) ^ (((m)&7) << 4)))

// == prep: Wa1|Wa2->bf16 (64) | W3->bf16 (8) | Wfuse (2) | pos->SoA (12) ==
__global__ __launch_bounds__(256) void k_prep(
        const float* __restrict__ Wa1f, const float* __restrict__ Wa2f,
        const float* __restrict__ W3f, const float* __restrict__ Wp2f,
        const float* __restrict__ pos,
        ushort_t* __restrict__ Wa1bf, ushort_t* __restrict__ Wa2bf,
        ushort_t* __restrict__ W3bf, ushort_t* __restrict__ Wfusebf,
        float* __restrict__ psoa) {
    int bid = blockIdx.x, tid = threadIdx.x;
    if (bid < 64) {
        int base = bid * 2048 + tid * 8;
        const float* src = (base < 65536) ? (Wa1f + base) : (Wa2f + (base - 65536));
        ushort_t* dst = (base < 65536) ? (Wa1bf + base) : (Wa2bf + (base - 65536));
        union { ushort_t u[8]; uint4 q; } pk;
        #pragma unroll
        for (int i = 0; i < 8; ++i) pk.u[i] = f2bf(src[i]);
        *(uint4*)dst = pk.q;
    } else if (bid < 72) {
        int base = (bid - 64) * 2048 + tid * 8;
        union { ushort_t u[8]; uint4 q; } pk;
        #pragma unroll
        for (int i = 0; i < 8; ++i) pk.u[i] = f2bf(W3f[base + i]);
        *(uint4*)&W3bf[base] = pk.q;
    } else if (bid < 74) {
        int a = (bid - 72) * 256 + tid;
        float s[PHH];
        #pragma unroll
        for (int jj = 0; jj < PHH; ++jj) s[jj] = 0.f;
        for (int d = 0; d < DD; ++d) {
            float wv = Wa1f[(size_t)a*DD + d];
            #pragma unroll
            for (int jj = 0; jj < PHH; ++jj) s[jj] += wv * Wp2f[d*PHH + jj];
        }
        union { ushort_t u[8]; uint4 q; } pk;
        #pragma unroll
        for (int jj = 0; jj < PHH; ++jj) pk.u[jj] = f2bf(s[jj]);
        *(uint4*)&Wfusebf[a*PHH] = pk.q;
    } else {
        // pos [2][4096][3] -> SoA px[2][4096] | py | pz (24576 floats)
        int e0 = (bid - 74) * 2048 + tid * 8;
        float v[8];
        #pragma unroll
        for (int i = 0; i < 8; ++i) {
            int el = e0 + i;
            int comp = el >> 13;           // 0..2
            int rem = el & 8191;           // b*4096 + j
            v[i] = pos[(size_t)rem*3 + comp];
        }
        #pragma unroll
        for (int i = 0; i < 8; i += 4)
            *(float4*)&psoa[e0 + i] = (float4){v[i], v[i+1], v[i+2], v[i+3]};
    }
}

// ==== front: lin1 + lin2 + qkv + single-pass QW/KW (MFMA); 32 pts/block ====
__global__ __launch_bounds__(256) void k_front(
        const float* __restrict__ x,
        const float* __restrict__ W1, const float* __restrict__ b1,
        const float* __restrict__ W2f, const float* __restrict__ b2,
        const float* __restrict__ Wqkvf,
        const ushort_t* __restrict__ Wa1bf, const float* __restrict__ ba1,
        float* __restrict__ h, ushort_t* __restrict__ vf,
        ushort_t* __restrict__ QWbf, ushort_t* __restrict__ KWbf) {
    __shared__ __align__(16) char smem[16896];
    float* xs = (float*)(smem + 16384);
    int tid = threadIdx.x, w = tid >> 6, lane = tid & 63;
    int lg = lane >> 4, c16 = lane & 15;
    int p0 = blockIdx.x * 32;

    if (tid < 96) xs[tid] = x[(size_t)p0*3 + tid];
    __syncthreads();

    #pragma unroll
    for (int it = 0; it < 16; ++it) {
        int lin = it*256 + tid;
        int m = lin >> 7, d = lin & 127;
        float hv = b1[d] + xs[m*3+0]*W1[d*3+0] + xs[m*3+1]*W1[d*3+1] + xs[m*3+2]*W1[d*3+2];
        h[(size_t)(p0+m)*DD + d] = hv;
        *(ushort_t*)&smem[SW256(m, d*2)] = f2bf(hv);
    }
    __syncthreads();

    {   // h1 = h@W2^T + b2 -> LDS @8192
        f32x4 acc[2][2];
        #pragma unroll
        for (int mt = 0; mt < 2; ++mt)
            #pragma unroll
            for (int ntl = 0; ntl < 2; ++ntl) acc[mt][ntl] = (f32x4){0,0,0,0};
        #pragma unroll
        for (int ks = 0; ks < 4; ++ks) {
            int k0 = ks*32 + lg*8;
            bf16x8 aF[2];
            #pragma unroll
            for (int mt = 0; mt < 2; ++mt)
                aF[mt] = *(const bf16x8*)&smem[SW256(mt*16 + c16, k0*2)];
            #pragma unroll
            for (int ntl = 0; ntl < 2; ++ntl) {
                int n = (2*w + ntl)*16 + c16;
                bf16x8 bF = load_bfrag(W2f + (size_t)n*DD + k0);
                #pragma unroll
                for (int mt = 0; mt < 2; ++mt)
                    acc[mt][ntl] = __builtin_amdgcn_mfma_f32_16x16x32_bf16(aF[mt], bF, acc[mt][ntl], 0, 0, 0);
            }
        }
        #pragma unroll
        for (int ntl = 0; ntl < 2; ++ntl) {
            int n = (2*w + ntl)*16 + c16;
            float bias = b2[n];
            #pragma unroll
            for (int mt = 0; mt < 2; ++mt)
                #pragma unroll
                for (int i = 0; i < 4; ++i) {
                    int m = mt*16 + lg*4 + i;
                    *(ushort_t*)&smem[8192 + SW256(m, n*2)] = f2bf(acc[mt][ntl][i] + bias);
                }
        }
    }
    __syncthreads();

    {   // qkv = h1@Wqkv^T: q -> LDS@0, k -> LDS@8192 (post-barrier), v -> global
        f32x4 acc[2][6];
        #pragma unroll
        for (int mt = 0; mt < 2; ++mt)
            #pragma unroll
            for (int ntl = 0; ntl < 6; ++ntl) acc[mt][ntl] = (f32x4){0,0,0,0};
        #pragma unroll
        for (int ks = 0; ks < 4; ++ks) {
            int k0 = ks*32 + lg*8;
            bf16x8 aF[2];
            #pragma unroll
            for (int mt = 0; mt < 2; ++mt)
                aF[mt] = *(const bf16x8*)&smem[8192 + SW256(mt*16 + c16, k0*2)];
            #pragma unroll
            for (int ntl = 0; ntl < 6; ++ntl) {
                int n = (w*6 + ntl)*16 + c16;
                bf16x8 bF = load_bfrag(Wqkvf + (size_t)n*DD + k0);
                #pragma unroll
                for (int mt = 0; mt < 2; ++mt)
                    acc[mt][ntl] = __builtin_amdgcn_mfma_f32_16x16x32_bf16(aF[mt], bF, acc[mt][ntl], 0, 0, 0);
            }
        }
        #pragma unroll
        for (int ntl = 0; ntl < 6; ++ntl) {
            int n = (w*6 + ntl)*16 + c16;
            int r = n >> 7, d = n & 127;
            #pragma unroll
            for (int mt = 0; mt < 2; ++mt)
                #pragma unroll
                for (int i = 0; i < 4; ++i) {
                    int m = mt*16 + lg*4 + i;
                    if (r == 0) *(ushort_t*)&smem[SW256(m, d*2)] = f2bf(acc[mt][ntl][i]);
                    else if (r == 2) vf[(size_t)(p0+m)*DD + d] = f2bf(acc[mt][ntl][i]);
                }
        }
        __syncthreads();
        #pragma unroll
        for (int ntl = 0; ntl < 6; ++ntl) {
            int n = (w*6 + ntl)*16 + c16;
            int r = n >> 7, d = n & 127;
            if (r == 1) {
                #pragma unroll
                for (int mt = 0; mt < 2; ++mt)
                    #pragma unroll
                    for (int i = 0; i < 4; ++i) {
                        int m = mt*16 + lg*4 + i;
                        *(ushort_t*)&smem[8192 + SW256(m, d*2)] = f2bf(acc[mt][ntl][i]);
                    }
            }
        }
    }
    __syncthreads();

    // single-pass QW/KW: each Wa1bf fragment feeds 4 MFMA (2 q-tiles + 2 k-tiles)
    #pragma unroll
    for (int half = 0; half < 2; ++half) {
        f32x4 accQ[2][4], accK[2][4];
        #pragma unroll
        for (int mt = 0; mt < 2; ++mt)
            #pragma unroll
            for (int ntl = 0; ntl < 4; ++ntl) {
                accQ[mt][ntl] = (f32x4){0,0,0,0};
                accK[mt][ntl] = (f32x4){0,0,0,0};
            }
        #pragma unroll
        for (int ks = 0; ks < 4; ++ks) {
            int k0 = ks*32 + lg*8;
            bf16x8 aQ[2], aK[2];
            #pragma unroll
            for (int mt = 0; mt < 2; ++mt) {
                aQ[mt] = *(const bf16x8*)&smem[SW256(mt*16 + c16, k0*2)];
                aK[mt] = *(const bf16x8*)&smem[8192 + SW256(mt*16 + c16, k0*2)];
            }
            #pragma unroll
            for (int ntl = 0; ntl < 4; ++ntl) {
                int n = (w*8 + half*4 + ntl)*16 + c16;
                bf16x8 bF = *(const bf16x8*)&Wa1bf[(size_t)n*DD + k0];
                #pragma unroll
                for (int mt = 0; mt < 2; ++mt) {
                    accQ[mt][ntl] = __builtin_amdgcn_mfma_f32_16x16x32_bf16(aQ[mt], bF, accQ[mt][ntl], 0, 0, 0);
                    accK[mt][ntl] = __builtin_amdgcn_mfma_f32_16x16x32_bf16(aK[mt], bF, accK[mt][ntl], 0, 0, 0);
                }
            }
        }
        #pragma unroll
        for (int ntl = 0; ntl < 4; ++ntl) {
            int n = (w*8 + half*4 + ntl)*16 + c16;
            float bias = ba1[n];
            #pragma unroll
            for (int mt = 0; mt < 2; ++mt)
                #pragma unroll
                for (int i = 0; i < 4; ++i) {
                    int m = mt*16 + lg*4 + i;
                    QWbf[(size_t)(p0+m)*AHH + n] = f2bf(accQ[mt][ntl][i] + bias);
                    KWbf[(size_t)(p0+m)*AHH + n] = f2bf(accK[mt][ntl][i]);
                }
        }
    }
}

// ------- KNN: one wave/query, SoA float4 candidates (4/lane/load) -------
__global__ __launch_bounds__(256) void k_knn(const float* __restrict__ pos,
                                             const float* __restrict__ psoa,
                                             int* __restrict__ idx) {
    int wid  = threadIdx.x >> 6;
    int lane = threadIdx.x & 63;
    int p = blockIdx.x*4 + wid;
    int b = p >> 12;
    float qx = pos[p*3+0], qy = pos[p*3+1], qz = pos[p*3+2];
    const float4* px4 = (const float4*)(psoa + (size_t)b*NN);
    const float4* py4 = (const float4*)(psoa + 8192 + (size_t)b*NN);
    const float4* pz4 = (const float4*)(psoa + 16384 + (size_t)b*NN);

    uint32_t bk[KNB];
    #pragma unroll
    for (int i = 0; i < KNB; ++i) bk[i] = 0xFFFFFFFFu;

    for (int it = 0; it < NN/256; ++it) {
        int j4 = it*64 + lane;
        float4 X = px4[j4], Y = py4[j4], Z = pz4[j4];
        #pragma unroll
        for (int c = 0; c < 4; ++c) {
            float dx = qx - ((c==0)?X.x:(c==1)?X.y:(c==2)?X.z:X.w);
            float dy = qy - ((c==0)?Y.x:(c==1)?Y.y:(c==2)?Y.z:Y.w);
            float dz = qz - ((c==0)?Z.x:(c==1)?Z.y:(c==2)?Z.z:Z.w);
            float d2 = dx*dx + dy*dy + dz*dz;
            uint32_t key = (__float_as_uint(d2) & 0xFFFFF000u) | (uint32_t)(j4*4 + c);
            if (key < bk[KNB-1]) {
                uint32_t cc = key;
                #pragma unroll
                for (int t = 0; t < KNB; ++t) {
                    uint32_t lo = umin32(cc, bk[t]);
                    uint32_t hi = umax32(cc, bk[t]);
                    bk[t] = lo; cc = hi;
                }
            }
        }
    }
    for (int r = 0; r < KNB; ++r) {
        uint32_t m = bk[0];
        #pragma unroll
        for (int s = 1; s < 64; s <<= 1)
            m = umin32(m, (uint32_t)__shfl_xor((int)m, s, 64));
        if (lane == 0) idx[(size_t)p*KNB + r] = (int)(m & 0xFFFu);
        bool win = (bk[0] == m);
        #pragma unroll
        for (int t = 0; t < KNB-1; ++t) bk[t] = win ? bk[t+1] : bk[t];
        bk[KNB-1] = win ? 0xFFFFFFFFu : bk[KNB-1];
    }
}

// ===== attn: r13 body + fused out-epilogue (LDS stays 22.5 KB) =====
// LDS: TL bf16[80][128] swz @0 (20480) | PH bf16[80][8] @20480 (1280) | NIDX @21760 (320)
// Epilogue reuses TL rows 0..15 as AGG[16][128] swz (rows 4..15 zeroed).
#define TL_OFF 0
#define PH_OFF 20480
#define NIDX_OFF 21760

__global__ __launch_bounds__(256, 4) void k_attn(
        const float* __restrict__ pos,
        const ushort_t* __restrict__ QWbf, const ushort_t* __restrict__ KWbf,
        const ushort_t* __restrict__ vf, const int* __restrict__ idx,
        const float* __restrict__ Wp1, const float* __restrict__ bp1,
        const float* __restrict__ Wp2, const float* __restrict__ bp2,
        const ushort_t* __restrict__ Wfusebf,
        const ushort_t* __restrict__ Wa2bf, const float* __restrict__ ba2,
        const ushort_t* __restrict__ W3bf, const float* __restrict__ b3,
        const float* __restrict__ h, float* __restrict__ out) {
    __shared__ __align__(16) char smem[22080];
    int* nidx = (int*)(smem + NIDX_OFF);

    int tid = threadIdx.x, w = tid >> 6, lane = tid & 63;
    int lg = lane >> 4, c16 = lane & 15;
    // XCD-batch swizzle: XCDs 0-3 -> batch 0, 4-7 -> batch 1
    int bid = blockIdx.x;
    int xcd = bid & 7, sloc = bid >> 3;
    int b = xcd >> 2;
    int p0 = b*NN + ((xcd & 3)*256 + sloc)*4;

    if (tid < 80) nidx[tid] = idx[(size_t)(p0 + tid/20)*KNB + (tid%20)];
    __syncthreads();

    // A1: pos-MLP hidden, packed bf16[8] per m-row
    if (tid < 80) {
        int m = tid, g = m / 20;
        int j = nidx[m];
        const float* pq = pos + (size_t)(p0+g)*3;
        const float* pn = pos + (size_t)(b*NN+j)*3;
        float r0 = pq[0]-pn[0], r1 = pq[1]-pn[1], r2 = pq[2]-pn[2];
        union { ushort_t u[8]; uint4 q; } pk;
        #pragma unroll
        for (int jj = 0; jj < PHH; ++jj) {
            float a = bp1[jj] + r0*Wp1[jj*3+0] + r1*Wp1[jj*3+1] + r2*Wp1[jj*3+2];
            pk.u[jj] = f2bf(fmaxf(a, 0.f));
        }
        *(uint4*)&smem[PH_OFF + m*16] = pk.q;
    }
    __syncthreads();

    int dA = w*32 + 2*c16, dB = dA + 1;   // adjacent d-pair per lane
    float bp2A = bp2[dA], bp2B = bp2[dB];
    float ba2A = ba2[dA], ba2B = ba2[dB];

    // vpe: pe-MFMA (K 8->32 pad, lg==0 carries) + v-gather (u32 pairs)
    bf16x8 bP0 = {0,0,0,0,0,0,0,0}, bP1 = {0,0,0,0,0,0,0,0};
    if (lg == 0) {
        bP0 = load_bfrag(Wp2 + (size_t)dA*PHH);
        bP1 = load_bfrag(Wp2 + (size_t)dB*PHH);
    }
    uint32_t vpe_pk[5][4];
    #pragma unroll
    for (int mt = 0; mt < 5; ++mt) {
        bf16x8 aP = {0,0,0,0,0,0,0,0};
        if (lg == 0) aP = *(const bf16x8*)&smem[PH_OFF + (mt*16 + c16)*16];
        f32x4 accP0 = (f32x4){0,0,0,0}, accP1 = (f32x4){0,0,0,0};
        accP0 = __builtin_amdgcn_mfma_f32_16x16x32_bf16(aP, bP0, accP0, 0, 0, 0);
        accP1 = __builtin_amdgcn_mfma_f32_16x16x32_bf16(aP, bP1, accP1, 0, 0, 0);
        #pragma unroll
        for (int i = 0; i < 4; ++i) {
            int m = mt*16 + lg*4 + i;
            int j = nidx[m];
            uint32_t vw = *(const uint32_t*)&vf[(size_t)(b*NN+j)*DD + dA];
            float peA = accP0[i] + bp2A;
            float peB = accP1[i] + bp2B;
            vpe_pk[mt][i] = cvt_pk_bf16(bf2f((ushort_t)(vw & 0xFFFFu)) + peA,
                                        bf2f((ushort_t)(vw >> 16)) + peB);
        }
    }

    // hidden in 4 chunks of 128; SIM in registers
    f32x4 accS[5][2];
    #pragma unroll
    for (int mt = 0; mt < 5; ++mt)
        #pragma unroll
        for (int ntl = 0; ntl < 2; ++ntl) accS[mt][ntl] = (f32x4){0,0,0,0};

    for (int c = 0; c < 4; ++c) {
        int aQ0 = c*128 + dA;
        // STAGE: T = relu(QWb - KW + pehid) -> TL (u32 pairs)
        bf16x8 bF0 = {0,0,0,0,0,0,0,0}, bF1 = {0,0,0,0,0,0,0,0};
        if (lg == 0) {
            bF0 = *(const bf16x8*)&Wfusebf[(size_t)aQ0*PHH];
            bF1 = *(const bf16x8*)&Wfusebf[(size_t)(aQ0+1)*PHH];
        }
        uint32_t qww[4];
        #pragma unroll
        for (int g = 0; g < 4; ++g)
            qww[g] = *(const uint32_t*)&QWbf[(size_t)(p0+g)*AHH + aQ0];
        uint32_t kwn[4];
        #pragma unroll
        for (int i = 0; i < 4; ++i)
            kwn[i] = *(const uint32_t*)&KWbf[(size_t)(b*NN + nidx[lg*4 + i])*AHH + aQ0];
        #pragma unroll
        for (int mt = 0; mt < 5; ++mt) {
            uint32_t kwc[4];
            #pragma unroll
            for (int i = 0; i < 4; ++i) kwc[i] = kwn[i];
            if (mt < 4) {
                #pragma unroll
                for (int i = 0; i < 4; ++i)
                    kwn[i] = *(const uint32_t*)&KWbf[(size_t)(b*NN + nidx[(mt+1)*16 + lg*4 + i])*AHH + aQ0];
            }
            bf16x8 aP = {0,0,0,0,0,0,0,0};
            if (lg == 0) aP = *(const bf16x8*)&smem[PH_OFF + (mt*16 + c16)*16];
            f32x4 accF0 = (f32x4){0,0,0,0}, accF1 = (f32x4){0,0,0,0};
            accF0 = __builtin_amdgcn_mfma_f32_16x16x32_bf16(aP, bF0, accF0, 0, 0, 0);
            accF1 = __builtin_amdgcn_mfma_f32_16x16x32_bf16(aP, bF1, accF1, 0, 0, 0);
            uint32_t qsel = (mt==0) ? qww[0]
                          : (mt==1) ? (lg>=1 ? qww[1] : qww[0])
                          : (mt==2) ? (lg>=2 ? qww[2] : qww[1])
                          : (mt==3) ? (lg==3 ? qww[3] : qww[2])
                          : qww[3];
            float qA = bf2f((ushort_t)(qsel & 0xFFFFu));
            float qB = bf2f((ushort_t)(qsel >> 16));
            #pragma unroll
            for (int i = 0; i < 4; ++i) {
                int m = mt*16 + lg*4 + i;
                float kA = bf2f((ushort_t)(kwc[i] & 0xFFFFu));
                float kB = bf2f((ushort_t)(kwc[i] >> 16));
                float tA = fmaxf(qA - kA + accF0[i], 0.f);
                float tB = fmaxf(qB - kB + accF1[i], 0.f);
                *(uint32_t*)&smem[TL_OFF + SW256(m, dA*2)] = cvt_pk_bf16(tA, tB);
            }
        }
        __syncthreads();

        // C: SIM += T_chunk @ Wa2_c^T
        __builtin_amdgcn_s_setprio(1);
        #pragma unroll
        for (int ks = 0; ks < 4; ++ks) {
            int k0 = ks*32 + lg*8;
            bf16x8 aF[5];
            #pragma unroll
            for (int mt = 0; mt < 5; ++mt)
                aF[mt] = *(const bf16x8*)&smem[TL_OFF + SW256(mt*16 + c16, k0*2)];
            bf16x8 bW0 = *(const bf16x8*)&Wa2bf[(size_t)dA*AHH + c*128 + k0];
            bf16x8 bW1 = *(const bf16x8*)&Wa2bf[(size_t)dB*AHH + c*128 + k0];
            #pragma unroll
            for (int mt = 0; mt < 5; ++mt) {
                accS[mt][0] = __builtin_amdgcn_mfma_f32_16x16x32_bf16(aF[mt], bW0, accS[mt][0], 0, 0, 0);
                accS[mt][1] = __builtin_amdgcn_mfma_f32_16x16x32_bf16(aF[mt], bW1, accS[mt][1], 0, 0, 0);
            }
        }
        __builtin_amdgcn_s_setprio(0);
        __syncthreads();
    }

    // D: in-register softmax over kk + aggregate (no max-subtract: |sim| ~ 1e-3)
    float s_mtA[5], a_mtA[5], s_mtB[5], a_mtB[5];
    #pragma unroll
    for (int mt = 0; mt < 5; ++mt) {
        float sa = 0.f, aa = 0.f, sb = 0.f, ab = 0.f;
        #pragma unroll
        for (int i = 0; i < 4; ++i) {
            float eA = __expf(accS[mt][0][i] + ba2A);
            float eB = __expf(accS[mt][1][i] + ba2B);
            uint32_t pk = vpe_pk[mt][i];
            float vA = bf2f((ushort_t)(pk & 0xFFFFu));
            float vB = bf2f((ushort_t)(pk >> 16));
            sa += eA; aa += eA*vA;
            sb += eB; ab += eB*vB;
        }
        s_mtA[mt] = sa; a_mtA[mt] = aa; s_mtB[mt] = sb; a_mtB[mt] = ab;
    }
    bool eq0 = (lg==0), ge1 = (lg>=1), ge2 = (lg>=2), le1 = (lg<=1), le2 = (lg<=2), eq3 = (lg==3);
    float s0A = s_mtA[0] + (eq0 ? s_mtA[1] : 0.f);
    float s1A = (ge1 ? s_mtA[1] : 0.f) + (le1 ? s_mtA[2] : 0.f);
    float s2A = (ge2 ? s_mtA[2] : 0.f) + (le2 ? s_mtA[3] : 0.f);
    float s3A = (eq3 ? s_mtA[3] : 0.f) + s_mtA[4];
    float a0A = a_mtA[0] + (eq0 ? a_mtA[1] : 0.f);
    float a1A = (ge1 ? a_mtA[1] : 0.f) + (le1 ? a_mtA[2] : 0.f);
    float a2A = (ge2 ? a_mtA[2] : 0.f) + (le2 ? a_mtA[3] : 0.f);
    float a3A = (eq3 ? a_mtA[3] : 0.f) + a_mtA[4];
    float s0B = s_mtB[0] + (eq0 ? s_mtB[1] : 0.f);
    float s1B = (ge1 ? s_mtB[1] : 0.f) + (le1 ? s_mtB[2] : 0.f);
    float s2B = (ge2 ? s_mtB[2] : 0.f) + (le2 ? s_mtB[3] : 0.f);
    float s3B = (eq3 ? s_mtB[3] : 0.f) + s_mtB[4];
    float a0B = a_mtB[0] + (eq0 ? a_mtB[1] : 0.f);
    float a1B = (ge1 ? a_mtB[1] : 0.f) + (le1 ? a_mtB[2] : 0.f);
    float a2B = (ge2 ? a_mtB[2] : 0.f) + (le2 ? a_mtB[3] : 0.f);
    float a3B = (eq3 ? a_mtB[3] : 0.f) + a_mtB[4];

    #define RED2(v) { v += __shfl_xor(v, 16, 64); v += __shfl_xor(v, 32, 64); }
    RED2(s0A) RED2(s1A) RED2(s2A) RED2(s3A)
    RED2(a0A) RED2(a1A) RED2(a2A) RED2(a3A)
    RED2(s0B) RED2(s1B) RED2(s2B) RED2(s3B)
    RED2(a0B) RED2(a1B) RED2(a2B) RED2(a3B)
    #undef RED2

    float myS_A = (lg==0) ? s0A : (lg==1) ? s1A : (lg==2) ? s2A : s3A;
    float myA_A = (lg==0) ? a0A : (lg==1) ? a1A : (lg==2) ? a2A : a3A;
    float myS_B = (lg==0) ? s0B : (lg==1) ? s1B : (lg==2) ? s2B : s3B;
    float myA_B = (lg==0) ? a0B : (lg==1) ? a1B : (lg==2) ? a2B : a3B;
    float aggA = myA_A / myS_A;
    float aggB = myA_B / myS_B;

    // ---- epilogue: out = h + agg @ W3^T + b3 (AGG in dead TL rows 0..15) ----
    #pragma unroll
    for (int z = 0; z < 3; ++z)          // zero rows 4..15 (bytes 1024..4095)
        *(uint32_t*)&smem[TL_OFF + 1024 + (z*256 + tid)*4] = 0u;
    *(uint32_t*)&smem[TL_OFF + SW256(lg, dA*2)] = cvt_pk_bf16(aggA, aggB);
    __syncthreads();

    f32x4 accO[2];
    accO[0] = (f32x4){0,0,0,0}; accO[1] = (f32x4){0,0,0,0};
    #pragma unroll
    for (int ks = 0; ks < 4; ++ks) {
        int k0 = ks*32 + lg*8;
        bf16x8 aF = *(const bf16x8*)&smem[TL_OFF + SW256(c16, k0*2)];
        #pragma unroll
        for (int ntl = 0; ntl < 2; ++ntl) {
            int n = (w*2 + ntl)*16 + c16;
            bf16x8 bF = *(const bf16x8*)&W3bf[(size_t)n*DD + k0];
            accO[ntl] = __builtin_amdgcn_mfma_f32_16x16x32_bf16(aF, bF, accO[ntl], 0, 0, 0);
        }
    }
    if (lg == 0) {
        #pragma unroll
        for (int ntl = 0; ntl < 2; ++ntl) {
            int n = (w*2 + ntl)*16 + c16;
            float bias = b3[n];
            #pragma unroll
            for (int i = 0; i < 4; ++i) {
                size_t o = (size_t)(p0+i)*DD + n;
                out[o] = accO[ntl][i] + bias + h[o];
            }
        }
    }
}

extern "C" void kernel_launch(void* const* d_in, const int* in_sizes, int n_in,
                              void* d_out, int out_size, void* d_ws, size_t ws_size,
                              hipStream_t stream) {
    const float* x    = (const float*)d_in[0];
    const float* pos  = (const float*)d_in[1];
    const float* W1   = (const float*)d_in[2];
    const float* b1   = (const float*)d_in[3];
    const float* W2   = (const float*)d_in[4];
    const float* b2   = (const float*)d_in[5];
    const float* W3   = (const float*)d_in[6];
    const float* b3   = (const float*)d_in[7];
    const float* Wqkv = (const float*)d_in[8];
    const float* Wp1  = (const float*)d_in[9];
    const float* bp1  = (const float*)d_in[10];
    const float* Wp2  = (const float*)d_in[11];
    const float* bp2  = (const float*)d_in[12];
    const float* Wa1  = (const float*)d_in[13];
    const float* ba1  = (const float*)d_in[14];
    const float* Wa2  = (const float*)d_in[15];
    const float* ba2  = (const float*)d_in[16];

    char* W = (char*)d_ws;
    float*    h       = (float*)(W + 0);          // 4 MB
    ushort_t* vf      = (ushort_t*)(W + 8388608); // 2 MB
    ushort_t* QWbf    = (ushort_t*)(W + 10485760);// 8 MB
    ushort_t* KWbf    = (ushort_t*)(W + 18874368);// 8 MB
    int*      idx     = (int*)(W + 27262976);     // 640 KB
    ushort_t* Wa1bf   = (ushort_t*)(W + 27918336);// 128 KB
    ushort_t* Wa2bf   = (ushort_t*)(W + 28049408);// 128 KB
    ushort_t* Wfusebf = (ushort_t*)(W + 28180480);// 8 KB
    float*    psoa    = (float*)(W + 28188672);   // 96 KB
    ushort_t* W3bf    = (ushort_t*)(W + 28286976);// 32 KB

    k_prep <<<86, 256, 0, stream>>>(Wa1, Wa2, W3, Wp2, pos,
                                    Wa1bf, Wa2bf, W3bf, Wfusebf, psoa);
    k_front<<<BN/32, 256, 0, stream>>>(x, W1, b1, W2, b2, Wqkv, Wa1bf, ba1,
                                       h, vf, QWbf, KWbf);
    k_knn  <<<BN/4, 256, 0, stream>>>(pos, psoa, idx);
    k_attn <<<BN/4, 256, 0, stream>>>(pos, QWbf, KWbf, vf, idx,
                                      Wp1, bp1, Wp2, bp2, Wfusebf, Wa2bf, ba2,
                                      W3bf, b3, h, (float*)d_out);
}

// Round 17
// 159.020 us; speedup vs baseline: 1.0241x; 1.0241x over previous
//
#include <hip/hip_runtime.h>
#include <stdint.h>

#define BB 2
#define NN 4096
#define KNB 20
#define DD 128
#define PHH 8
#define AHH 512
#define BN (BB*NN)

typedef unsigned short ushort_t;
typedef short bf16x8 __attribute__((ext_vector_type(8)));
typedef float f32x4 __attribute__((ext_vector_type(4)));

__device__ __forceinline__ uint32_t umin32(uint32_t a, uint32_t b) { return a < b ? a : b; }
__device__ __forceinline__ uint32_t umax32(uint32_t a, uint32_t b) { return a > b ? a : b; }

__device__ __forceinline__ float bf2f(ushort_t u) {
    union { float f; uint32_t i; } c; c.i = ((uint32_t)u) << 16; return c.f;
}
__device__ __forceinline__ uint32_t cvt_pk_bf16(float lo, float hi) {
    uint32_t r;
    asm("v_cvt_pk_bf16_f32 %0, %1, %2" : "=v"(r) : "v"(lo), "v"(hi));
    return r;  // lo16 = bf16(lo), hi16 = bf16(hi)
}
__device__ __forceinline__ ushort_t f2bf(float f) {   // single-instr RNE via cvt_pk
    return (ushort_t)(cvt_pk_bf16(f, f) & 0xFFFFu);
}
__device__ __forceinline__ bf16x8 load_bfrag(const float* __restrict__ src) {
    float4 x = *(const float4*)src;
    float4 y = *(const float4*)(src + 4);
    union { bf16x8 v; uint32_t u[4]; } r;
    r.u[0] = cvt_pk_bf16(x.x, x.y);
    r.u[1] = cvt_pk_bf16(x.z, x.w);
    r.u[2] = cvt_pk_bf16(y.x, y.y);
    r.u[3] = cvt_pk_bf16(y.z, y.w);
    return r.v;
}

#define SW256(m, byteInRow) ((m)*256 + ((byteInRow) ^ (((m)&7) << 4)))

// == prep: Wa1|Wa2(64) | W3(8) | W2(8) | Wqkv(24) ->bf16 | Wfuse(2) | pos->SoA(12) ==
__global__ __launch_bounds__(256) void k_prep(
        const float* __restrict__ Wa1f, const float* __restrict__ Wa2f,
        const float* __restrict__ W3f, const float* __restrict__ W2f,
        const float* __restrict__ Wqkvf, const float* __restrict__ Wp2f,
        const float* __restrict__ pos,
        ushort_t* __restrict__ Wa1bf, ushort_t* __restrict__ Wa2bf,
        ushort_t* __restrict__ W3bf, ushort_t* __restrict__ W2bf,
        ushort_t* __restrict__ Wqkvbf, ushort_t* __restrict__ Wfusebf,
        float* __restrict__ psoa) {
    int bid = blockIdx.x, tid = threadIdx.x;
    if (bid < 64) {
        int base = bid * 2048 + tid * 8;
        const float* src = (base < 65536) ? (Wa1f + base) : (Wa2f + (base - 65536));
        ushort_t* dst = (base < 65536) ? (Wa1bf + base) : (Wa2bf + (base - 65536));
        union { ushort_t u[8]; uint4 q; } pk;
        #pragma unroll
        for (int i = 0; i < 8; ++i) pk.u[i] = f2bf(src[i]);
        *(uint4*)dst = pk.q;
    } else if (bid < 72) {
        int base = (bid - 64) * 2048 + tid * 8;
        union { ushort_t u[8]; uint4 q; } pk;
        #pragma unroll
        for (int i = 0; i < 8; ++i) pk.u[i] = f2bf(W3f[base + i]);
        *(uint4*)&W3bf[base] = pk.q;
    } else if (bid < 80) {
        int base = (bid - 72) * 2048 + tid * 8;
        union { ushort_t u[8]; uint4 q; } pk;
        #pragma unroll
        for (int i = 0; i < 8; ++i) pk.u[i] = f2bf(W2f[base + i]);
        *(uint4*)&W2bf[base] = pk.q;
    } else if (bid < 104) {
        int base = (bid - 80) * 2048 + tid * 8;
        union { ushort_t u[8]; uint4 q; } pk;
        #pragma unroll
        for (int i = 0; i < 8; ++i) pk.u[i] = f2bf(Wqkvf[base + i]);
        *(uint4*)&Wqkvbf[base] = pk.q;
    } else if (bid < 106) {
        int a = (bid - 104) * 256 + tid;
        float s[PHH];
        #pragma unroll
        for (int jj = 0; jj < PHH; ++jj) s[jj] = 0.f;
        for (int d = 0; d < DD; ++d) {
            float wv = Wa1f[(size_t)a*DD + d];
            #pragma unroll
            for (int jj = 0; jj < PHH; ++jj) s[jj] += wv * Wp2f[d*PHH + jj];
        }
        union { ushort_t u[8]; uint4 q; } pk;
        #pragma unroll
        for (int jj = 0; jj < PHH; ++jj) pk.u[jj] = f2bf(s[jj]);
        *(uint4*)&Wfusebf[a*PHH] = pk.q;
    } else {
        // pos [2][4096][3] -> SoA px[2][4096] | py | pz (24576 floats)
        int e0 = (bid - 106) * 2048 + tid * 8;
        float v[8];
        #pragma unroll
        for (int i = 0; i < 8; ++i) {
            int el = e0 + i;
            int comp = el >> 13;           // 0..2
            int rem = el & 8191;           // b*4096 + j
            v[i] = pos[(size_t)rem*3 + comp];
        }
        #pragma unroll
        for (int i = 0; i < 8; i += 4)
            *(float4*)&psoa[e0 + i] = (float4){v[i], v[i+1], v[i+2], v[i+3]};
    }
}

// ==== front: lin1 + lin2 + qkv + single-pass QW/KW (MFMA, all-bf16 weights) ====
__global__ __launch_bounds__(256) void k_front(
        const float* __restrict__ x,
        const float* __restrict__ W1, const float* __restrict__ b1,
        const ushort_t* __restrict__ W2bf, const float* __restrict__ b2,
        const ushort_t* __restrict__ Wqkvbf,
        const ushort_t* __restrict__ Wa1bf, const float* __restrict__ ba1,
        float* __restrict__ h, ushort_t* __restrict__ vf,
        ushort_t* __restrict__ QWbf, ushort_t* __restrict__ KWbf) {
    __shared__ __align__(16) char smem[16896];
    float* xs = (float*)(smem + 16384);
    int tid = threadIdx.x, w = tid >> 6, lane = tid & 63;
    int lg = lane >> 4, c16 = lane & 15;
    int p0 = blockIdx.x * 32;

    if (tid < 96) xs[tid] = x[(size_t)p0*3 + tid];
    __syncthreads();

    #pragma unroll
    for (int it = 0; it < 16; ++it) {
        int lin = it*256 + tid;
        int m = lin >> 7, d = lin & 127;
        float hv = b1[d] + xs[m*3+0]*W1[d*3+0] + xs[m*3+1]*W1[d*3+1] + xs[m*3+2]*W1[d*3+2];
        h[(size_t)(p0+m)*DD + d] = hv;
        *(ushort_t*)&smem[SW256(m, d*2)] = f2bf(hv);
    }
    __syncthreads();

    {   // h1 = h@W2^T + b2 -> LDS @8192
        f32x4 acc[2][2];
        #pragma unroll
        for (int mt = 0; mt < 2; ++mt)
            #pragma unroll
            for (int ntl = 0; ntl < 2; ++ntl) acc[mt][ntl] = (f32x4){0,0,0,0};
        #pragma unroll
        for (int ks = 0; ks < 4; ++ks) {
            int k0 = ks*32 + lg*8;
            bf16x8 aF[2];
            #pragma unroll
            for (int mt = 0; mt < 2; ++mt)
                aF[mt] = *(const bf16x8*)&smem[SW256(mt*16 + c16, k0*2)];
            #pragma unroll
            for (int ntl = 0; ntl < 2; ++ntl) {
                int n = (2*w + ntl)*16 + c16;
                bf16x8 bF = *(const bf16x8*)&W2bf[(size_t)n*DD + k0];
                #pragma unroll
                for (int mt = 0; mt < 2; ++mt)
                    acc[mt][ntl] = __builtin_amdgcn_mfma_f32_16x16x32_bf16(aF[mt], bF, acc[mt][ntl], 0, 0, 0);
            }
        }
        #pragma unroll
        for (int ntl = 0; ntl < 2; ++ntl) {
            int n = (2*w + ntl)*16 + c16;
            float bias = b2[n];
            #pragma unroll
            for (int mt = 0; mt < 2; ++mt)
                #pragma unroll
                for (int i = 0; i < 4; ++i) {
                    int m = mt*16 + lg*4 + i;
                    *(ushort_t*)&smem[8192 + SW256(m, n*2)] = f2bf(acc[mt][ntl][i] + bias);
                }
        }
    }
    __syncthreads();

    {   // qkv = h1@Wqkv^T: q -> LDS@0, k -> LDS@8192 (post-barrier), v -> global
        f32x4 acc[2][6];
        #pragma unroll
        for (int mt = 0; mt < 2; ++mt)
            #pragma unroll
            for (int ntl = 0; ntl < 6; ++ntl) acc[mt][ntl] = (f32x4){0,0,0,0};
        #pragma unroll
        for (int ks = 0; ks < 4; ++ks) {
            int k0 = ks*32 + lg*8;
            bf16x8 aF[2];
            #pragma unroll
            for (int mt = 0; mt < 2; ++mt)
                aF[mt] = *(const bf16x8*)&smem[8192 + SW256(mt*16 + c16, k0*2)];
            #pragma unroll
            for (int ntl = 0; ntl < 6; ++ntl) {
                int n = (w*6 + ntl)*16 + c16;
                bf16x8 bF = *(const bf16x8*)&Wqkvbf[(size_t)n*DD + k0];
                #pragma unroll
                for (int mt = 0; mt < 2; ++mt)
                    acc[mt][ntl] = __builtin_amdgcn_mfma_f32_16x16x32_bf16(aF[mt], bF, acc[mt][ntl], 0, 0, 0);
            }
        }
        #pragma unroll
        for (int ntl = 0; ntl < 6; ++ntl) {
            int n = (w*6 + ntl)*16 + c16;
            int r = n >> 7, d = n & 127;
            #pragma unroll
            for (int mt = 0; mt < 2; ++mt)
                #pragma unroll
                for (int i = 0; i < 4; ++i) {
                    int m = mt*16 + lg*4 + i;
                    if (r == 0) *(ushort_t*)&smem[SW256(m, d*2)] = f2bf(acc[mt][ntl][i]);
                    else if (r == 2) vf[(size_t)(p0+m)*DD + d] = f2bf(acc[mt][ntl][i]);
                }
        }
        __syncthreads();
        #pragma unroll
        for (int ntl = 0; ntl < 6; ++ntl) {
            int n = (w*6 + ntl)*16 + c16;
            int r = n >> 7, d = n & 127;
            if (r == 1) {
                #pragma unroll
                for (int mt = 0; mt < 2; ++mt)
                    #pragma unroll
                    for (int i = 0; i < 4; ++i) {
                        int m = mt*16 + lg*4 + i;
                        *(ushort_t*)&smem[8192 + SW256(m, d*2)] = f2bf(acc[mt][ntl][i]);
                    }
            }
        }
    }
    __syncthreads();

    // single-pass QW/KW: each Wa1bf fragment feeds 4 MFMA (2 q-tiles + 2 k-tiles)
    #pragma unroll
    for (int half = 0; half < 2; ++half) {
        f32x4 accQ[2][4], accK[2][4];
        #pragma unroll
        for (int mt = 0; mt < 2; ++mt)
            #pragma unroll
            for (int ntl = 0; ntl < 4; ++ntl) {
                accQ[mt][ntl] = (f32x4){0,0,0,0};
                accK[mt][ntl] = (f32x4){0,0,0,0};
            }
        #pragma unroll
        for (int ks = 0; ks < 4; ++ks) {
            int k0 = ks*32 + lg*8;
            bf16x8 aQ[2], aK[2];
            #pragma unroll
            for (int mt = 0; mt < 2; ++mt) {
                aQ[mt] = *(const bf16x8*)&smem[SW256(mt*16 + c16, k0*2)];
                aK[mt] = *(const bf16x8*)&smem[8192 + SW256(mt*16 + c16, k0*2)];
            }
            #pragma unroll
            for (int ntl = 0; ntl < 4; ++ntl) {
                int n = (w*8 + half*4 + ntl)*16 + c16;
                bf16x8 bF = *(const bf16x8*)&Wa1bf[(size_t)n*DD + k0];
                #pragma unroll
                for (int mt = 0; mt < 2; ++mt) {
                    accQ[mt][ntl] = __builtin_amdgcn_mfma_f32_16x16x32_bf16(aQ[mt], bF, accQ[mt][ntl], 0, 0, 0);
                    accK[mt][ntl] = __builtin_amdgcn_mfma_f32_16x16x32_bf16(aK[mt], bF, accK[mt][ntl], 0, 0, 0);
                }
            }
        }
        #pragma unroll
        for (int ntl = 0; ntl < 4; ++ntl) {
            int n = (w*8 + half*4 + ntl)*16 + c16;
            float bias = ba1[n];
            #pragma unroll
            for (int mt = 0; mt < 2; ++mt)
                #pragma unroll
                for (int i = 0; i < 4; ++i) {
                    int m = mt*16 + lg*4 + i;
                    QWbf[(size_t)(p0+m)*AHH + n] = f2bf(accQ[mt][ntl][i] + bias);
                    KWbf[(size_t)(p0+m)*AHH + n] = f2bf(accK[mt][ntl][i]);
                }
        }
    }
}

// ------- KNN: one wave/query, SoA float4 candidates (4/lane/load) -------
__global__ __launch_bounds__(256) void k_knn(const float* __restrict__ pos,
                                             const float* __restrict__ psoa,
                                             int* __restrict__ idx) {
    int wid  = threadIdx.x >> 6;
    int lane = threadIdx.x & 63;
    int p = blockIdx.x*4 + wid;
    int b = p >> 12;
    float qx = pos[p*3+0], qy = pos[p*3+1], qz = pos[p*3+2];
    const float4* px4 = (const float4*)(psoa + (size_t)b*NN);
    const float4* py4 = (const float4*)(psoa + 8192 + (size_t)b*NN);
    const float4* pz4 = (const float4*)(psoa + 16384 + (size_t)b*NN);

    uint32_t bk[KNB];
    #pragma unroll
    for (int i = 0; i < KNB; ++i) bk[i] = 0xFFFFFFFFu;

    for (int it = 0; it < NN/256; ++it) {
        int j4 = it*64 + lane;
        float4 X = px4[j4], Y = py4[j4], Z = pz4[j4];
        #pragma unroll
        for (int c = 0; c < 4; ++c) {
            float dx = qx - ((c==0)?X.x:(c==1)?X.y:(c==2)?X.z:X.w);
            float dy = qy - ((c==0)?Y.x:(c==1)?Y.y:(c==2)?Y.z:Y.w);
            float dz = qz - ((c==0)?Z.x:(c==1)?Z.y:(c==2)?Z.z:Z.w);
            float d2 = dx*dx + dy*dy + dz*dz;
            uint32_t key = (__float_as_uint(d2) & 0xFFFFF000u) | (uint32_t)(j4*4 + c);
            if (key < bk[KNB-1]) {
                uint32_t cc = key;
                #pragma unroll
                for (int t = 0; t < KNB; ++t) {
                    uint32_t lo = umin32(cc, bk[t]);
                    uint32_t hi = umax32(cc, bk[t]);
                    bk[t] = lo; cc = hi;
                }
            }
        }
    }
    for (int r = 0; r < KNB; ++r) {
        uint32_t m = bk[0];
        #pragma unroll
        for (int s = 1; s < 64; s <<= 1)
            m = umin32(m, (uint32_t)__shfl_xor((int)m, s, 64));
        if (lane == 0) idx[(size_t)p*KNB + r] = (int)(m & 0xFFFu);
        bool win = (bk[0] == m);
        #pragma unroll
        for (int t = 0; t < KNB-1; ++t) bk[t] = win ? bk[t+1] : bk[t];
        bk[KNB-1] = win ? 0xFFFFFFFFu : bk[KNB-1];
    }
}

// ===== attn: r13 body + fused out-epilogue with h-hoist (LDS 22.5 KB) =====
#define TL_OFF 0
#define PH_OFF 20480
#define NIDX_OFF 21760

__global__ __launch_bounds__(256, 4) void k_attn(
        const float* __restrict__ pos,
        const ushort_t* __restrict__ QWbf, const ushort_t* __restrict__ KWbf,
        const ushort_t* __restrict__ vf, const int* __restrict__ idx,
        const float* __restrict__ Wp1, const float* __restrict__ bp1,
        const float* __restrict__ Wp2, const float* __restrict__ bp2,
        const ushort_t* __restrict__ Wfusebf,
        const ushort_t* __restrict__ Wa2bf, const float* __restrict__ ba2,
        const ushort_t* __restrict__ W3bf, const float* __restrict__ b3,
        const float* __restrict__ h, float* __restrict__ out) {
    __shared__ __align__(16) char smem[22080];
    int* nidx = (int*)(smem + NIDX_OFF);

    int tid = threadIdx.x, w = tid >> 6, lane = tid & 63;
    int lg = lane >> 4, c16 = lane & 15;
    // XCD-batch swizzle: XCDs 0-3 -> batch 0, 4-7 -> batch 1
    int bid = blockIdx.x;
    int xcd = bid & 7, sloc = bid >> 3;
    int b = xcd >> 2;
    int p0 = b*NN + ((xcd & 3)*256 + sloc)*4;

    if (tid < 80) nidx[tid] = idx[(size_t)(p0 + tid/20)*KNB + (tid%20)];
    __syncthreads();

    // A1: pos-MLP hidden, packed bf16[8] per m-row
    if (tid < 80) {
        int m = tid, g = m / 20;
        int j = nidx[m];
        const float* pq = pos + (size_t)(p0+g)*3;
        const float* pn = pos + (size_t)(b*NN+j)*3;
        float r0 = pq[0]-pn[0], r1 = pq[1]-pn[1], r2 = pq[2]-pn[2];
        union { ushort_t u[8]; uint4 q; } pk;
        #pragma unroll
        for (int jj = 0; jj < PHH; ++jj) {
            float a = bp1[jj] + r0*Wp1[jj*3+0] + r1*Wp1[jj*3+1] + r2*Wp1[jj*3+2];
            pk.u[jj] = f2bf(fmaxf(a, 0.f));
        }
        *(uint4*)&smem[PH_OFF + m*16] = pk.q;
    }
    __syncthreads();

    int dA = w*32 + 2*c16, dB = dA + 1;   // adjacent d-pair per lane
    float bp2A = bp2[dA], bp2B = bp2[dB];
    float ba2A = ba2[dA], ba2B = ba2[dB];

    // vpe: pe-MFMA (K 8->32 pad, lg==0 carries) + v-gather (u32 pairs)
    bf16x8 bP0 = {0,0,0,0,0,0,0,0}, bP1 = {0,0,0,0,0,0,0,0};
    if (lg == 0) {
        bP0 = load_bfrag(Wp2 + (size_t)dA*PHH);
        bP1 = load_bfrag(Wp2 + (size_t)dB*PHH);
    }
    uint32_t vpe_pk[5][4];
    #pragma unroll
    for (int mt = 0; mt < 5; ++mt) {
        bf16x8 aP = {0,0,0,0,0,0,0,0};
        if (lg == 0) aP = *(const bf16x8*)&smem[PH_OFF + (mt*16 + c16)*16];
        f32x4 accP0 = (f32x4){0,0,0,0}, accP1 = (f32x4){0,0,0,0};
        accP0 = __builtin_amdgcn_mfma_f32_16x16x32_bf16(aP, bP0, accP0, 0, 0, 0);
        accP1 = __builtin_amdgcn_mfma_f32_16x16x32_bf16(aP, bP1, accP1, 0, 0, 0);
        #pragma unroll
        for (int i = 0; i < 4; ++i) {
            int m = mt*16 + lg*4 + i;
            int j = nidx[m];
            uint32_t vw = *(const uint32_t*)&vf[(size_t)(b*NN+j)*DD + dA];
            float peA = accP0[i] + bp2A;
            float peB = accP1[i] + bp2B;
            vpe_pk[mt][i] = cvt_pk_bf16(bf2f((ushort_t)(vw & 0xFFFFu)) + peA,
                                        bf2f((ushort_t)(vw >> 16)) + peB);
        }
    }

    // hidden in 4 chunks of 128; SIM in registers
    f32x4 accS[5][2];
    #pragma unroll
    for (int mt = 0; mt < 5; ++mt)
        #pragma unroll
        for (int ntl = 0; ntl < 2; ++ntl) accS[mt][ntl] = (f32x4){0,0,0,0};

    for (int c = 0; c < 4; ++c) {
        int aQ0 = c*128 + dA;
        // STAGE: T = relu(QWb - KW + pehid) -> TL (u32 pairs)
        bf16x8 bF0 = {0,0,0,0,0,0,0,0}, bF1 = {0,0,0,0,0,0,0,0};
        if (lg == 0) {
            bF0 = *(const bf16x8*)&Wfusebf[(size_t)aQ0*PHH];
            bF1 = *(const bf16x8*)&Wfusebf[(size_t)(aQ0+1)*PHH];
        }
        uint32_t qww[4];
        #pragma unroll
        for (int g = 0; g < 4; ++g)
            qww[g] = *(const uint32_t*)&QWbf[(size_t)(p0+g)*AHH + aQ0];
        uint32_t kwn[4];
        #pragma unroll
        for (int i = 0; i < 4; ++i)
            kwn[i] = *(const uint32_t*)&KWbf[(size_t)(b*NN + nidx[lg*4 + i])*AHH + aQ0];
        #pragma unroll
        for (int mt = 0; mt < 5; ++mt) {
            uint32_t kwc[4];
            #pragma unroll
            for (int i = 0; i < 4; ++i) kwc[i] = kwn[i];
            if (mt < 4) {
                #pragma unroll
                for (int i = 0; i < 4; ++i)
                    kwn[i] = *(const uint32_t*)&KWbf[(size_t)(b*NN + nidx[(mt+1)*16 + lg*4 + i])*AHH + aQ0];
            }
            bf16x8 aP = {0,0,0,0,0,0,0,0};
            if (lg == 0) aP = *(const bf16x8*)&smem[PH_OFF + (mt*16 + c16)*16];
            f32x4 accF0 = (f32x4){0,0,0,0}, accF1 = (f32x4){0,0,0,0};
            accF0 = __builtin_amdgcn_mfma_f32_16x16x32_bf16(aP, bF0, accF0, 0, 0, 0);
            accF1 = __builtin_amdgcn_mfma_f32_16x16x32_bf16(aP, bF1, accF1, 0, 0, 0);
            uint32_t qsel = (mt==0) ? qww[0]
                          : (mt==1) ? (lg>=1 ? qww[1] : qww[0])
                          : (mt==2) ? (lg>=2 ? qww[2] : qww[1])
                          : (mt==3) ? (lg==3 ? qww[3] : qww[2])
                          : qww[3];
            float qA = bf2f((ushort_t)(qsel & 0xFFFFu));
            float qB = bf2f((ushort_t)(qsel >> 16));
            #pragma unroll
            for (int i = 0; i < 4; ++i) {
                int m = mt*16 + lg*4 + i;
                float kA = bf2f((ushort_t)(kwc[i] & 0xFFFFu));
                float kB = bf2f((ushort_t)(kwc[i] >> 16));
                float tA = fmaxf(qA - kA + accF0[i], 0.f);
                float tB = fmaxf(qB - kB + accF1[i], 0.f);
                *(uint32_t*)&smem[TL_OFF + SW256(m, dA*2)] = cvt_pk_bf16(tA, tB);
            }
        }
        __syncthreads();

        // C: SIM += T_chunk @ Wa2_c^T
        __builtin_amdgcn_s_setprio(1);
        #pragma unroll
        for (int ks = 0; ks < 4; ++ks) {
            int k0 = ks*32 + lg*8;
            bf16x8 aF[5];
            #pragma unroll
            for (int mt = 0; mt < 5; ++mt)
                aF[mt] = *(const bf16x8*)&smem[TL_OFF + SW256(mt*16 + c16, k0*2)];
            bf16x8 bW0 = *(const bf16x8*)&Wa2bf[(size_t)dA*AHH + c*128 + k0];
            bf16x8 bW1 = *(const bf16x8*)&Wa2bf[(size_t)dB*AHH + c*128 + k0];
            #pragma unroll
            for (int mt = 0; mt < 5; ++mt) {
                accS[mt][0] = __builtin_amdgcn_mfma_f32_16x16x32_bf16(aF[mt], bW0, accS[mt][0], 0, 0, 0);
                accS[mt][1] = __builtin_amdgcn_mfma_f32_16x16x32_bf16(aF[mt], bW1, accS[mt][1], 0, 0, 0);
            }
        }
        __builtin_amdgcn_s_setprio(0);
        __syncthreads();
    }

    // D: in-register softmax over kk + aggregate (no max-subtract: |sim| ~ 1e-3)
    float s_mtA[5], a_mtA[5], s_mtB[5], a_mtB[5];
    #pragma unroll
    for (int mt = 0; mt < 5; ++mt) {
        float sa = 0.f, aa = 0.f, sb = 0.f, ab = 0.f;
        #pragma unroll
        for (int i = 0; i < 4; ++i) {
            float eA = __expf(accS[mt][0][i] + ba2A);
            float eB = __expf(accS[mt][1][i] + ba2B);
            uint32_t pk = vpe_pk[mt][i];
            float vA = bf2f((ushort_t)(pk & 0xFFFFu));
            float vB = bf2f((ushort_t)(pk >> 16));
            sa += eA; aa += eA*vA;
            sb += eB; ab += eB*vB;
        }
        s_mtA[mt] = sa; a_mtA[mt] = aa; s_mtB[mt] = sb; a_mtB[mt] = ab;
    }
    bool eq0 = (lg==0), ge1 = (lg>=1), ge2 = (lg>=2), le1 = (lg<=1), le2 = (lg<=2), eq3 = (lg==3);
    float s0A = s_mtA[0] + (eq0 ? s_mtA[1] : 0.f);
    float s1A = (ge1 ? s_mtA[1] : 0.f) + (le1 ? s_mtA[2] : 0.f);
    float s2A = (ge2 ? s_mtA[2] : 0.f) + (le2 ? s_mtA[3] : 0.f);
    float s3A = (eq3 ? s_mtA[3] : 0.f) + s_mtA[4];
    float a0A = a_mtA[0] + (eq0 ? a_mtA[1] : 0.f);
    float a1A = (ge1 ? a_mtA[1] : 0.f) + (le1 ? a_mtA[2] : 0.f);
    float a2A = (ge2 ? a_mtA[2] : 0.f) + (le2 ? a_mtA[3] : 0.f);
    float a3A = (eq3 ? a_mtA[3] : 0.f) + a_mtA[4];
    float s0B = s_mtB[0] + (eq0 ? s_mtB[1] : 0.f);
    float s1B = (ge1 ? s_mtB[1] : 0.f) + (le1 ? s_mtB[2] : 0.f);
    float s2B = (ge2 ? s_mtB[2] : 0.f) + (le2 ? s_mtB[3] : 0.f);
    float s3B = (eq3 ? s_mtB[3] : 0.f) + s_mtB[4];
    float a0B = a_mtB[0] + (eq0 ? a_mtB[1] : 0.f);
    float a1B = (ge1 ? a_mtB[1] : 0.f) + (le1 ? a_mtB[2] : 0.f);
    float a2B = (ge2 ? a_mtB[2] : 0.f) + (le2 ? a_mtB[3] : 0.f);
    float a3B = (eq3 ? a_mtB[3] : 0.f) + a_mtB[4];

    #define RED2(v) { v += __shfl_xor(v, 16, 64); v += __shfl_xor(v, 32, 64); }
    RED2(s0A) RED2(s1A) RED2(s2A) RED2(s3A)
    RED2(a0A) RED2(a1A) RED2(a2A) RED2(a3A)
    RED2(s0B) RED2(s1B) RED2(s2B) RED2(s3B)
    RED2(a0B) RED2(a1B) RED2(a2B) RED2(a3B)
    #undef RED2

    float myS_A = (lg==0) ? s0A : (lg==1) ? s1A : (lg==2) ? s2A : s3A;
    float myA_A = (lg==0) ? a0A : (lg==1) ? a1A : (lg==2) ? a2A : a3A;
    float myS_B = (lg==0) ? s0B : (lg==1) ? s1B : (lg==2) ? s2B : s3B;
    float myA_B = (lg==0) ? a0B : (lg==1) ? a1B : (lg==2) ? a2B : a3B;
    float aggA = myA_A / myS_A;
    float aggB = myA_B / myS_B;

    // ---- epilogue: out = h + agg @ W3^T + b3 (AGG in dead TL rows 0..15) ----
    // hoist h loads NOW so HBM latency hides under zero/store/barrier/MFMA
    float hv[2][4];
    if (lg == 0) {
        #pragma unroll
        for (int ntl = 0; ntl < 2; ++ntl) {
            int n = (w*2 + ntl)*16 + c16;
            #pragma unroll
            for (int i = 0; i < 4; ++i)
                hv[ntl][i] = h[(size_t)(p0+i)*DD + n];
        }
    }
    #pragma unroll
    for (int z = 0; z < 3; ++z)          // zero rows 4..15 (bytes 1024..4095)
        *(uint32_t*)&smem[TL_OFF + 1024 + (z*256 + tid)*4] = 0u;
    *(uint32_t*)&smem[TL_OFF + SW256(lg, dA*2)] = cvt_pk_bf16(aggA, aggB);
    __syncthreads();

    f32x4 accO[2];
    accO[0] = (f32x4){0,0,0,0}; accO[1] = (f32x4){0,0,0,0};
    #pragma unroll
    for (int ks = 0; ks < 4; ++ks) {
        int k0 = ks*32 + lg*8;
        bf16x8 aF = *(const bf16x8*)&smem[TL_OFF + SW256(c16, k0*2)];
        #pragma unroll
        for (int ntl = 0; ntl < 2; ++ntl) {
            int n = (w*2 + ntl)*16 + c16;
            bf16x8 bF = *(const bf16x8*)&W3bf[(size_t)n*DD + k0];
            accO[ntl] = __builtin_amdgcn_mfma_f32_16x16x32_bf16(aF, bF, accO[ntl], 0, 0, 0);
        }
    }
    if (lg == 0) {
        #pragma unroll
        for (int ntl = 0; ntl < 2; ++ntl) {
            int n = (w*2 + ntl)*16 + c16;
            float bias = b3[n];
            #pragma unroll
            for (int i = 0; i < 4; ++i) {
                size_t o = (size_t)(p0+i)*DD + n;
                out[o] = accO[ntl][i] + bias + hv[ntl][i];
            }
        }
    }
}

extern "C" void kernel_launch(void* const* d_in, const int* in_sizes, int n_in,
                              void* d_out, int out_size, void* d_ws, size_t ws_size,
                              hipStream_t stream) {
    const float* x    = (const float*)d_in[0];
    const float* pos  = (const float*)d_in[1];
    const float* W1   = (const float*)d_in[2];
    const float* b1   = (const float*)d_in[3];
    const float* W2   = (const float*)d_in[4];
    const float* b2   = (const float*)d_in[5];
    const float* W3   = (const float*)d_in[6];
    const float* b3   = (const float*)d_in[7];
    const float* Wqkv = (const float*)d_in[8];
    const float* Wp1  = (const float*)d_in[9];
    const float* bp1  = (const float*)d_in[10];
    const float* Wp2  = (const float*)d_in[11];
    const float* bp2  = (const float*)d_in[12];
    const float* Wa1  = (const float*)d_in[13];
    const float* ba1  = (const float*)d_in[14];
    const float* Wa2  = (const float*)d_in[15];
    const float* ba2  = (const float*)d_in[16];

    char* W = (char*)d_ws;
    float*    h       = (float*)(W + 0);          // 4 MB
    ushort_t* vf      = (ushort_t*)(W + 8388608); // 2 MB
    ushort_t* QWbf    = (ushort_t*)(W + 10485760);// 8 MB
    ushort_t* KWbf    = (ushort_t*)(W + 18874368);// 8 MB
    int*      idx     = (int*)(W + 27262976);     // 640 KB
    ushort_t* Wa1bf   = (ushort_t*)(W + 27918336);// 128 KB
    ushort_t* Wa2bf   = (ushort_t*)(W + 28049408);// 128 KB
    ushort_t* Wfusebf = (ushort_t*)(W + 28180480);// 8 KB
    float*    psoa    = (float*)(W + 28188672);   // 96 KB
    ushort_t* W3bf    = (ushort_t*)(W + 28286976);// 32 KB
    ushort_t* W2bf    = (ushort_t*)(W + 28319744);// 32 KB
    ushort_t* Wqkvbf  = (ushort_t*)(W + 28352512);// 96 KB

    k_prep <<<118, 256, 0, stream>>>(Wa1, Wa2, W3, W2, Wqkv, Wp2, pos,
                                     Wa1bf, Wa2bf, W3bf, W2bf, Wqkvbf, Wfusebf, psoa);
    k_front<<<BN/32, 256, 0, stream>>>(x, W1, b1, W2bf, b2, Wqkvbf, Wa1bf, ba1,
                                       h, vf, QWbf, KWbf);
    k_knn  <<<BN/4, 256, 0, stream>>>(pos, psoa, idx);
    k_attn <<<BN/4, 256, 0, stream>>>(pos, QWbf, KWbf, vf, idx,
                                      Wp1, bp1, Wp2, bp2, Wfusebf, Wa2bf, ba2,
                                      W3bf, b3, h, (float*)d_out);
}